// Round 11
// baseline (131.805 us; speedup 1.0000x reference)
//
#include <hip/hip_runtime.h>

// Problem constants (match reference)
#define NBATCH   16
#define NUMATOM  512
#define NEIGH    48
#define NPAIR    (NUMATOM * NEIGH)        // 24576
#define TOTNATOM (NBATCH * NUMATOM)       // 8192
#define NTYPE    4
#define NWAVE    8
#define OUT_PER_ATOM 96                    // 4 types x 3 orders x 8 waves

#define APB    8                           // atoms per block (1 per wave)
#define GPB    (NUMATOM / APB)             // 64 atom-groups per batch
#define NGRP   (NBATCH * GPB)              // 1024 groups total
#define CAP    96                          // per-atom queue capacity (max occ ~75)
#define GCAP   512                         // per-group bucket capacity (E=384, +6.6 sigma)
#define NCHUNK 12                          // scan chunks per batch (2048 pairs each)

// ---------------------------------------------------------------------------
// Kernel A: single coalesced scan of all i0 lists (each batch row scanned
// exactly once). Deposits p | (atom_in_group << 16) into per-group global
// buckets. One global int atomic per pair.
// ---------------------------------------------------------------------------
__global__ __launch_bounds__(512) void bucket_pairs(
        const int* __restrict__ atom_index,
        int*       __restrict__ gcnt,      // [NGRP], pre-zeroed
        int*       __restrict__ gbucket) { // [NGRP][GCAP]
    int blk = blockIdx.x;
    int b   = blk / NCHUNK;
    int ch  = blk - b * NCHUNK;
    int t   = threadIdx.x;

    const int* i0row = atom_index + ((size_t)b * 2 + 0) * NPAIR + ch * 2048;

#pragma unroll
    for (int k = 0; k < 4; ++k) {
        int i  = t + k * 512;
        int p  = ch * 2048 + i;
        int a0 = i0row[i];
        int gid  = b * GPB + (a0 >> 3);
        int slot = atomicAdd(&gcnt[gid], 1);
        if (slot < GCAP)
            gbucket[(size_t)gid * GCAP + slot] = p | ((a0 & (APB - 1)) << 16);
    }
}

// ---------------------------------------------------------------------------
// Kernel B: round-9 fused kernel with phase 1 replaced by a coalesced bucket
// read + LDS re-bin. Block = 512 threads = 8 waves; wave wv owns atom lo+wv.
// Phase 2a: full-lane geometry for queued pairs. Phase 2b: dense register
// accumulation (lane = (row j, wave w)), explicit 4x unroll, shuffle-
// butterfly order binning, direct output write.
// Rows: 0..2 = ux,uy,uz ; 3..5 = xx,yy,zz ; 6,7 = xy,xz ; row 8 (yz) carried
// by lanes 0..7 in a second accumulator. Order1 = sum(diag^2)+2*sum(offdiag^2).
// ---------------------------------------------------------------------------
__global__ __launch_bounds__(512, 4) void fused_density(
        const float* __restrict__ coords,
        const int*   __restrict__ atom_index,
        const float* __restrict__ shifts,
        const int*   __restrict__ species,
        const float* __restrict__ rs,
        const float* __restrict__ inta,
        const int*   __restrict__ gcnt,
        const int*   __restrict__ gbucket,
        float*       __restrict__ out) {
    __shared__ float  lc[NUMATOM * 3];     //  6144 B: batch coordinates
    __shared__ int    dq[APB * CAP];       //  3072 B: pair-index queues
    __shared__ float4 pq[APB * CAP];       // 12288 B: (u, r) descriptors
    __shared__ int    qn[APB];
    __shared__ int    lsp[APB];
    __shared__ float  lrs[NTYPE * NWAVE];
    __shared__ float  lia[NTYPE * NWAVE];

    int blk = blockIdx.x;                  // == group id
    int b   = blk >> 6;                    // batch
    int g   = blk & (GPB - 1);             // atom group
    int t   = threadIdx.x;
    int lo  = g * APB;                     // first local atom of this block

    const float* cb = coords + (size_t)b * NUMATOM * 3;
    for (int i = t; i < NUMATOM * 3; i += 512) lc[i] = cb[i];
    if (t < NTYPE * NWAVE) { lrs[t] = rs[t]; lia[t] = -10.0f * inta[t]; }
    if (t < APB) { qn[t] = 0; lsp[t] = species[b * NUMATOM + lo + t]; }
    __syncthreads();

    // ---- Phase 1: coalesced bucket read + LDS re-bin
    int n = gcnt[blk]; if (n > GCAP) n = GCAP;
    const int* gb = gbucket + (size_t)blk * GCAP;
    for (int i = t; i < n; i += 512) {
        int e  = gb[i];
        int al = e >> 16;
        int s  = atomicAdd(&qn[al], 1);
        if (s < CAP) dq[al * CAP + s] = e & 0xFFFF;
    }
    __syncthreads();

    int wv = t >> 6;                       // wave id == local atom index
    int l  = t & 63;
    int c  = qn[wv]; if (c > CAP) c = CAP;

    const int*   i1row = atom_index + ((size_t)b * 2 + 1) * NPAIR;
    const float* shrow = shifts + (size_t)b * NPAIR * 3;

    // ---- Phase 2a: full-lane geometry into float4 queue
    int ga0 = 3 * (lo + wv);
    for (int k = l; k < c; k += 64) {
        int p  = dq[wv * CAP + k];
        int a1 = i1row[p];
        float dx = lc[ga0 + 0] - lc[3 * a1 + 0] + shrow[3 * p + 0];
        float dy = lc[ga0 + 1] - lc[3 * a1 + 1] + shrow[3 * p + 1];
        float dz = lc[ga0 + 2] - lc[3 * a1 + 2] + shrow[3 * p + 2];
        float r   = sqrtf(dx * dx + dy * dy + dz * dz);
        float inv = 1.0f / r;
        pq[wv * CAP + k] = make_float4(dx * inv, dy * inv, dz * inv, r);
    }
    __syncthreads();

    // ---- Phase 2b: dense register accumulation, explicit 4x unroll
    int sp = lsp[wv];
    int j  = l >> 3, w = l & 7;
    float rw = lrs[sp * NWAVE + w];
    float cw = lia[sp * NWAVE + w];

    int ia, ib;                            // ang = u[ia]*u[ib]; ib==3 -> 1.0
    if (j < 3)       { ia = j;     ib = 3;     }
    else if (j < 6)  { ia = j - 3; ib = j - 3; }
    else if (j == 6) { ia = 0;     ib = 1;     }
    else             { ia = 0;     ib = 2;     }

    const float4* q = pq + wv * CAP;
    float acc = 0.0f, acc2 = 0.0f;
    int k = 0;
    for (; k + 4 <= c; k += 4) {
        float4 v0 = q[k];
        float4 v1 = q[k + 1];
        float4 v2 = q[k + 2];
        float4 v3 = q[k + 3];
        float d0 = v0.w - rw, d1 = v1.w - rw, d2 = v2.w - rw, d3 = v3.w - rw;
        float g0 = __expf(cw * d0 * d0);
        float g1 = __expf(cw * d1 * d1);
        float g2 = __expf(cw * d2 * d2);
        float g3 = __expf(cw * d3 * d3);
        float ua0 = (ia == 0) ? v0.x : (ia == 1) ? v0.y : v0.z;
        float ub0 = (ib == 0) ? v0.x : (ib == 1) ? v0.y : (ib == 2) ? v0.z : 1.0f;
        float ua1 = (ia == 0) ? v1.x : (ia == 1) ? v1.y : v1.z;
        float ub1 = (ib == 0) ? v1.x : (ib == 1) ? v1.y : (ib == 2) ? v1.z : 1.0f;
        float ua2 = (ia == 0) ? v2.x : (ia == 1) ? v2.y : v2.z;
        float ub2 = (ib == 0) ? v2.x : (ib == 1) ? v2.y : (ib == 2) ? v2.z : 1.0f;
        float ua3 = (ia == 0) ? v3.x : (ia == 1) ? v3.y : v3.z;
        float ub3 = (ib == 0) ? v3.x : (ib == 1) ? v3.y : (ib == 2) ? v3.z : 1.0f;
        acc  += ua0 * ub0 * g0 + ua1 * ub1 * g1
              + ua2 * ub2 * g2 + ua3 * ub3 * g3;
        acc2 += v0.y * v0.z * g0 + v1.y * v1.z * g1
              + v2.y * v2.z * g2 + v3.y * v3.z * g3;
    }
    for (; k < c; ++k) {
        float4 v = q[k];
        float d = v.w - rw;
        float gg = __expf(cw * d * d);
        float ua = (ia == 0) ? v.x : (ia == 1) ? v.y : v.z;
        float ub = (ib == 0) ? v.x : (ib == 1) ? v.y : (ib == 2) ? v.z : 1.0f;
        acc  += ua * ub * gg;
        acc2 += v.y * v.z * gg;
    }

    // ---- Order binning via shuffle butterflies
    float dens = acc * acc;
    float A = (j < 3) ? dens : 0.0f;                         // order 0
    float B = (j >= 3 && j < 6) ? dens                       // diag
            : (j >= 6) ? 2.0f * dens : 0.0f;                 // xy,xz doubled
    if (l < 8) B = 2.0f * acc2 * acc2;                       // yz doubled (j==0 lanes)

#pragma unroll
    for (int m = 8; m < 64; m <<= 1) {
        A += __shfl_xor(A, m);
        B += __shfl_xor(B, m);
    }
    // every lane now holds ord0/ord1 for its w = l&7

    // ---- Output: 96 floats for atom a (only species block nonzero)
    int a = (b << 9) + lo + wv;
    float* ob = out + (size_t)a * OUT_PER_ATOM;
    {
        int o = l, ity = o / 24, rem = o % 24, od = rem >> 3;
        ob[o] = (ity == sp && od < 2) ? (od == 0 ? A : B) : 0.0f;
    }
    if (l < 32) {
        int o = l + 64, ity = o / 24, rem = o % 24, od = rem >> 3;
        ob[o] = (ity == sp && od < 2) ? (od == 0 ? A : B) : 0.0f;
    }
}

// ---------------------------------------------------------------------------

extern "C" void kernel_launch(void* const* d_in, const int* in_sizes, int n_in,
                              void* d_out, int out_size, void* d_ws, size_t ws_size,
                              hipStream_t stream) {
    const float* coords     = (const float*)d_in[0];
    // d_in[1] = numatoms (unused by the math)
    const int*   atom_index = (const int*)  d_in[2];
    const float* shifts     = (const float*)d_in[3];
    const int*   species    = (const int*)  d_in[4];
    const float* rs         = (const float*)d_in[5];
    const float* inta       = (const float*)d_in[6];
    float*       out        = (float*)      d_out;

    const size_t cnt_bytes = (size_t)NGRP * sizeof(int);       // 4 KB
    const size_t gb_off    = (cnt_bytes + 255) & ~(size_t)255;
    int* gcnt    = (int*)d_ws;
    int* gbucket = (int*)((char*)d_ws + gb_off);               // 2 MB

    hipMemsetAsync(gcnt, 0, cnt_bytes, stream);

    bucket_pairs<<<NBATCH * NCHUNK, 512, 0, stream>>>(atom_index, gcnt, gbucket);

    fused_density<<<NGRP, 512, 0, stream>>>(
        coords, atom_index, shifts, species, rs, inta, gcnt, gbucket, out);
}

// Round 12
// 96.493 us; speedup vs baseline: 1.3659x; 1.3659x over previous
//
#include <hip/hip_runtime.h>

// Problem constants (match reference)
#define NBATCH   16
#define NUMATOM  512
#define NEIGH    48
#define NPAIR    (NUMATOM * NEIGH)        // 24576
#define TOTNATOM (NBATCH * NUMATOM)       // 8192
#define NTYPE    4
#define NWAVE    8
#define OUT_PER_ATOM 96                    // 4 types x 3 orders x 8 waves

#define APB   16                           // atoms per block (1 per wave)
#define TPB   (APB * 64)                   // 1024 threads
#define GPB   (NUMATOM / APB)              // 32 atom-groups per batch
#define CAP   96                           // per-atom queue capacity (max occ ~75)

// ---------------------------------------------------------------------------
// Single fused kernel (round-9 structure, 16 waves/block). Wave wv owns atom
// lo+wv of batch b. Phase 1: coalesced scan of the batch's i0 list (24
// iters/thread; 32x redundancy per batch, halved vs APB=8), enqueue pair
// indices per atom (LDS). Phase 2a: full-lane geometry for queued pairs.
// Phase 2b: dense register accumulation (lane = (row j, wave w)), explicit
// 4x unroll, shuffle-butterfly order binning, direct output write.
// Rows: 0..2 = ux,uy,uz ; 3..5 = xx,yy,zz ; 6,7 = xy,xz ; row 8 (yz) carried
// by lanes 0..7 in a second accumulator. Order1 = sum(diag^2)+2*sum(offdiag^2).
// ---------------------------------------------------------------------------
__global__ __launch_bounds__(TPB, 2) void fused_density(
        const float* __restrict__ coords,
        const int*   __restrict__ atom_index,
        const float* __restrict__ shifts,
        const int*   __restrict__ species,
        const float* __restrict__ rs,
        const float* __restrict__ inta,
        float*       __restrict__ out) {
    __shared__ float  lc[NUMATOM * 3];     //  6144 B: batch coordinates
    __shared__ int    dq[APB * CAP];       //  6144 B: pair-index queues
    __shared__ float4 pq[APB * CAP];       // 24576 B: (u, r) descriptors
    __shared__ int    qn[APB];
    __shared__ int    lsp[APB];
    __shared__ float  lrs[NTYPE * NWAVE];
    __shared__ float  lia[NTYPE * NWAVE];

    int blk = blockIdx.x;
    int b   = blk / GPB;                   // batch
    int g   = blk - b * GPB;               // atom group
    int t   = threadIdx.x;
    int lo  = g * APB;                     // first local atom of this block

    const float* cb = coords + (size_t)b * NUMATOM * 3;
    for (int i = t; i < NUMATOM * 3; i += TPB) lc[i] = cb[i];
    if (t < NTYPE * NWAVE) { lrs[t] = rs[t]; lia[t] = -10.0f * inta[t]; }
    if (t < APB) { qn[t] = 0; lsp[t] = species[b * NUMATOM + lo + t]; }
    __syncthreads();

    const int*   i0row = atom_index + ((size_t)b * 2 + 0) * NPAIR;
    const int*   i1row = atom_index + ((size_t)b * 2 + 1) * NPAIR;
    const float* shrow = shifts + (size_t)b * NPAIR * 3;

    // ---- Phase 1: scan + enqueue (coalesced reads; 24 iters/thread)
#pragma unroll 4
    for (int p = t; p < NPAIR; p += TPB) {
        int a0 = i0row[p];
        if ((a0 >> 4) == g) {
            int al = a0 & (APB - 1);
            int s  = atomicAdd(&qn[al], 1);
            if (s < CAP) dq[al * CAP + s] = p;
        }
    }
    __syncthreads();

    int wv = t >> 6;                       // wave id == local atom index
    int l  = t & 63;
    int c  = qn[wv]; if (c > CAP) c = CAP;

    // ---- Phase 2a: full-lane geometry into float4 queue
    int ga0 = 3 * (lo + wv);
    for (int k = l; k < c; k += 64) {
        int p  = dq[wv * CAP + k];
        int a1 = i1row[p];
        float dx = lc[ga0 + 0] - lc[3 * a1 + 0] + shrow[3 * p + 0];
        float dy = lc[ga0 + 1] - lc[3 * a1 + 1] + shrow[3 * p + 1];
        float dz = lc[ga0 + 2] - lc[3 * a1 + 2] + shrow[3 * p + 2];
        float r   = sqrtf(dx * dx + dy * dy + dz * dz);
        float inv = 1.0f / r;
        pq[wv * CAP + k] = make_float4(dx * inv, dy * inv, dz * inv, r);
    }
    __syncthreads();

    // ---- Phase 2b: dense register accumulation, explicit 4x unroll
    int sp = lsp[wv];
    int j  = l >> 3, w = l & 7;
    float rw = lrs[sp * NWAVE + w];
    float cw = lia[sp * NWAVE + w];

    int ia, ib;                            // ang = u[ia]*u[ib]; ib==3 -> 1.0
    if (j < 3)       { ia = j;     ib = 3;     }
    else if (j < 6)  { ia = j - 3; ib = j - 3; }
    else if (j == 6) { ia = 0;     ib = 1;     }
    else             { ia = 0;     ib = 2;     }

    const float4* q = pq + wv * CAP;
    float acc = 0.0f, acc2 = 0.0f;
    int k = 0;
    for (; k + 4 <= c; k += 4) {
        float4 v0 = q[k];
        float4 v1 = q[k + 1];
        float4 v2 = q[k + 2];
        float4 v3 = q[k + 3];
        float d0 = v0.w - rw, d1 = v1.w - rw, d2 = v2.w - rw, d3 = v3.w - rw;
        float g0 = __expf(cw * d0 * d0);
        float g1 = __expf(cw * d1 * d1);
        float g2 = __expf(cw * d2 * d2);
        float g3 = __expf(cw * d3 * d3);
        float ua0 = (ia == 0) ? v0.x : (ia == 1) ? v0.y : v0.z;
        float ub0 = (ib == 0) ? v0.x : (ib == 1) ? v0.y : (ib == 2) ? v0.z : 1.0f;
        float ua1 = (ia == 0) ? v1.x : (ia == 1) ? v1.y : v1.z;
        float ub1 = (ib == 0) ? v1.x : (ib == 1) ? v1.y : (ib == 2) ? v1.z : 1.0f;
        float ua2 = (ia == 0) ? v2.x : (ia == 1) ? v2.y : v2.z;
        float ub2 = (ib == 0) ? v2.x : (ib == 1) ? v2.y : (ib == 2) ? v2.z : 1.0f;
        float ua3 = (ia == 0) ? v3.x : (ia == 1) ? v3.y : v3.z;
        float ub3 = (ib == 0) ? v3.x : (ib == 1) ? v3.y : (ib == 2) ? v3.z : 1.0f;
        acc  += ua0 * ub0 * g0 + ua1 * ub1 * g1
              + ua2 * ub2 * g2 + ua3 * ub3 * g3;
        acc2 += v0.y * v0.z * g0 + v1.y * v1.z * g1
              + v2.y * v2.z * g2 + v3.y * v3.z * g3;
    }
    for (; k < c; ++k) {
        float4 v = q[k];
        float d = v.w - rw;
        float gg = __expf(cw * d * d);
        float ua = (ia == 0) ? v.x : (ia == 1) ? v.y : v.z;
        float ub = (ib == 0) ? v.x : (ib == 1) ? v.y : (ib == 2) ? v.z : 1.0f;
        acc  += ua * ub * gg;
        acc2 += v.y * v.z * gg;
    }

    // ---- Order binning via shuffle butterflies
    float dens = acc * acc;
    float A = (j < 3) ? dens : 0.0f;                         // order 0
    float B = (j >= 3 && j < 6) ? dens                       // diag
            : (j >= 6) ? 2.0f * dens : 0.0f;                 // xy,xz doubled
    if (l < 8) B = 2.0f * acc2 * acc2;                       // yz doubled (j==0 lanes)

#pragma unroll
    for (int m = 8; m < 64; m <<= 1) {
        A += __shfl_xor(A, m);
        B += __shfl_xor(B, m);
    }
    // every lane now holds ord0/ord1 for its w = l&7

    // ---- Output: 96 floats for atom a (only species block nonzero)
    int a = (b << 9) + lo + wv;
    float* ob = out + (size_t)a * OUT_PER_ATOM;
    {
        int o = l, ity = o / 24, rem = o % 24, od = rem >> 3;
        ob[o] = (ity == sp && od < 2) ? (od == 0 ? A : B) : 0.0f;
    }
    if (l < 32) {
        int o = l + 64, ity = o / 24, rem = o % 24, od = rem >> 3;
        ob[o] = (ity == sp && od < 2) ? (od == 0 ? A : B) : 0.0f;
    }
}

// ---------------------------------------------------------------------------

extern "C" void kernel_launch(void* const* d_in, const int* in_sizes, int n_in,
                              void* d_out, int out_size, void* d_ws, size_t ws_size,
                              hipStream_t stream) {
    const float* coords     = (const float*)d_in[0];
    // d_in[1] = numatoms (unused by the math)
    const int*   atom_index = (const int*)  d_in[2];
    const float* shifts     = (const float*)d_in[3];
    const int*   species    = (const int*)  d_in[4];
    const float* rs         = (const float*)d_in[5];
    const float* inta       = (const float*)d_in[6];
    float*       out        = (float*)      d_out;

    fused_density<<<NBATCH * GPB, TPB, 0, stream>>>(
        coords, atom_index, shifts, species, rs, inta, out);
}

// Round 13
// 91.282 us; speedup vs baseline: 1.4439x; 1.0571x over previous
//
#include <hip/hip_runtime.h>

// Problem constants (match reference)
#define NBATCH   16
#define NUMATOM  512
#define NEIGH    48
#define NPAIR    (NUMATOM * NEIGH)        // 24576
#define TOTNATOM (NBATCH * NUMATOM)       // 8192
#define NTYPE    4
#define NWAVE    8
#define OUT_PER_ATOM 96                    // 4 types x 3 orders x 8 waves

#define APB   16                           // atoms per block (1 per wave)
#define TPB   (APB * 64)                   // 1024 threads
#define GPB   (NUMATOM / APB)              // 32 atom-groups per batch
#define CAP   96                           // per-atom queue capacity (max occ ~75)

// ---------------------------------------------------------------------------
// Single fused kernel (round-12 structure + XCD-aware block swizzle).
// Launch index wgid = (b%8) + 8*(g + 32*(b/8)) so wgid%8 (the XCD on the
// 8-XCD MI355X dispatch round-robin) is constant per batch: each XCD owns
// exactly 2 complete batches -> i0/shifts/coords stay L2-resident per XCD.
// Wave wv owns atom lo+wv of batch b. Phase 1: coalesced scan of the batch's
// i0 list, enqueue pair indices per atom (LDS). Phase 2a: full-lane geometry.
// Phase 2b: dense register accumulation, explicit 4x unroll, shuffle-
// butterfly order binning, direct output write.
// Rows: 0..2 = ux,uy,uz ; 3..5 = xx,yy,zz ; 6,7 = xy,xz ; row 8 (yz) carried
// by lanes 0..7 in a second accumulator. Order1 = sum(diag^2)+2*sum(offdiag^2).
// ---------------------------------------------------------------------------
__global__ __launch_bounds__(TPB, 2) void fused_density(
        const float* __restrict__ coords,
        const int*   __restrict__ atom_index,
        const float* __restrict__ shifts,
        const int*   __restrict__ species,
        const float* __restrict__ rs,
        const float* __restrict__ inta,
        float*       __restrict__ out) {
    __shared__ float  lc[NUMATOM * 3];     //  6144 B: batch coordinates
    __shared__ int    dq[APB * CAP];       //  6144 B: pair-index queues
    __shared__ float4 pq[APB * CAP];       // 24576 B: (u, r) descriptors
    __shared__ int    qn[APB];
    __shared__ int    lsp[APB];
    __shared__ float  lrs[NTYPE * NWAVE];
    __shared__ float  lia[NTYPE * NWAVE];

    // ---- XCD-aware decode: wgid = (b%8) + 8*(g + 32*(b/8))
    int wgid = blockIdx.x;
    int kk   = wgid >> 3;                  // g + 32*(b/8)
    int b    = (wgid & 7) + 8 * (kk >> 5); // batch
    int g    = kk & 31;                    // atom group
    int t    = threadIdx.x;
    int lo   = g * APB;                    // first local atom of this block

    const float* cb = coords + (size_t)b * NUMATOM * 3;
    for (int i = t; i < NUMATOM * 3; i += TPB) lc[i] = cb[i];
    if (t < NTYPE * NWAVE) { lrs[t] = rs[t]; lia[t] = -10.0f * inta[t]; }
    if (t < APB) { qn[t] = 0; lsp[t] = species[b * NUMATOM + lo + t]; }
    __syncthreads();

    const int*   i0row = atom_index + ((size_t)b * 2 + 0) * NPAIR;
    const int*   i1row = atom_index + ((size_t)b * 2 + 1) * NPAIR;
    const float* shrow = shifts + (size_t)b * NPAIR * 3;

    // ---- Phase 1: scan + enqueue (coalesced reads; 24 iters/thread)
#pragma unroll 4
    for (int p = t; p < NPAIR; p += TPB) {
        int a0 = i0row[p];
        if ((a0 >> 4) == g) {
            int al = a0 & (APB - 1);
            int s  = atomicAdd(&qn[al], 1);
            if (s < CAP) dq[al * CAP + s] = p;
        }
    }
    __syncthreads();

    int wv = t >> 6;                       // wave id == local atom index
    int l  = t & 63;
    int c  = qn[wv]; if (c > CAP) c = CAP;

    // ---- Phase 2a: full-lane geometry into float4 queue
    int ga0 = 3 * (lo + wv);
    for (int k = l; k < c; k += 64) {
        int p  = dq[wv * CAP + k];
        int a1 = i1row[p];
        float dx = lc[ga0 + 0] - lc[3 * a1 + 0] + shrow[3 * p + 0];
        float dy = lc[ga0 + 1] - lc[3 * a1 + 1] + shrow[3 * p + 1];
        float dz = lc[ga0 + 2] - lc[3 * a1 + 2] + shrow[3 * p + 2];
        float r   = sqrtf(dx * dx + dy * dy + dz * dz);
        float inv = 1.0f / r;
        pq[wv * CAP + k] = make_float4(dx * inv, dy * inv, dz * inv, r);
    }
    __syncthreads();

    // ---- Phase 2b: dense register accumulation, explicit 4x unroll
    int sp = lsp[wv];
    int j  = l >> 3, w = l & 7;
    float rw = lrs[sp * NWAVE + w];
    float cw = lia[sp * NWAVE + w];

    int ia, ib;                            // ang = u[ia]*u[ib]; ib==3 -> 1.0
    if (j < 3)       { ia = j;     ib = 3;     }
    else if (j < 6)  { ia = j - 3; ib = j - 3; }
    else if (j == 6) { ia = 0;     ib = 1;     }
    else             { ia = 0;     ib = 2;     }

    const float4* q = pq + wv * CAP;
    float acc = 0.0f, acc2 = 0.0f;
    int k = 0;
    for (; k + 4 <= c; k += 4) {
        float4 v0 = q[k];
        float4 v1 = q[k + 1];
        float4 v2 = q[k + 2];
        float4 v3 = q[k + 3];
        float d0 = v0.w - rw, d1 = v1.w - rw, d2 = v2.w - rw, d3 = v3.w - rw;
        float g0 = __expf(cw * d0 * d0);
        float g1 = __expf(cw * d1 * d1);
        float g2 = __expf(cw * d2 * d2);
        float g3 = __expf(cw * d3 * d3);
        float ua0 = (ia == 0) ? v0.x : (ia == 1) ? v0.y : v0.z;
        float ub0 = (ib == 0) ? v0.x : (ib == 1) ? v0.y : (ib == 2) ? v0.z : 1.0f;
        float ua1 = (ia == 0) ? v1.x : (ia == 1) ? v1.y : v1.z;
        float ub1 = (ib == 0) ? v1.x : (ib == 1) ? v1.y : (ib == 2) ? v1.z : 1.0f;
        float ua2 = (ia == 0) ? v2.x : (ia == 1) ? v2.y : v2.z;
        float ub2 = (ib == 0) ? v2.x : (ib == 1) ? v2.y : (ib == 2) ? v2.z : 1.0f;
        float ua3 = (ia == 0) ? v3.x : (ia == 1) ? v3.y : v3.z;
        float ub3 = (ib == 0) ? v3.x : (ib == 1) ? v3.y : (ib == 2) ? v3.z : 1.0f;
        acc  += ua0 * ub0 * g0 + ua1 * ub1 * g1
              + ua2 * ub2 * g2 + ua3 * ub3 * g3;
        acc2 += v0.y * v0.z * g0 + v1.y * v1.z * g1
              + v2.y * v2.z * g2 + v3.y * v3.z * g3;
    }
    for (; k < c; ++k) {
        float4 v = q[k];
        float d = v.w - rw;
        float gg = __expf(cw * d * d);
        float ua = (ia == 0) ? v.x : (ia == 1) ? v.y : v.z;
        float ub = (ib == 0) ? v.x : (ib == 1) ? v.y : (ib == 2) ? v.z : 1.0f;
        acc  += ua * ub * gg;
        acc2 += v.y * v.z * gg;
    }

    // ---- Order binning via shuffle butterflies
    float dens = acc * acc;
    float A = (j < 3) ? dens : 0.0f;                         // order 0
    float B = (j >= 3 && j < 6) ? dens                       // diag
            : (j >= 6) ? 2.0f * dens : 0.0f;                 // xy,xz doubled
    if (l < 8) B = 2.0f * acc2 * acc2;                       // yz doubled (j==0 lanes)

#pragma unroll
    for (int m = 8; m < 64; m <<= 1) {
        A += __shfl_xor(A, m);
        B += __shfl_xor(B, m);
    }
    // every lane now holds ord0/ord1 for its w = l&7

    // ---- Output: 96 floats for atom a (only species block nonzero)
    int a = (b << 9) + lo + wv;
    float* ob = out + (size_t)a * OUT_PER_ATOM;
    {
        int o = l, ity = o / 24, rem = o % 24, od = rem >> 3;
        ob[o] = (ity == sp && od < 2) ? (od == 0 ? A : B) : 0.0f;
    }
    if (l < 32) {
        int o = l + 64, ity = o / 24, rem = o % 24, od = rem >> 3;
        ob[o] = (ity == sp && od < 2) ? (od == 0 ? A : B) : 0.0f;
    }
}

// ---------------------------------------------------------------------------

extern "C" void kernel_launch(void* const* d_in, const int* in_sizes, int n_in,
                              void* d_out, int out_size, void* d_ws, size_t ws_size,
                              hipStream_t stream) {
    const float* coords     = (const float*)d_in[0];
    // d_in[1] = numatoms (unused by the math)
    const int*   atom_index = (const int*)  d_in[2];
    const float* shifts     = (const float*)d_in[3];
    const int*   species    = (const int*)  d_in[4];
    const float* rs         = (const float*)d_in[5];
    const float* inta       = (const float*)d_in[6];
    float*       out        = (float*)      d_out;

    fused_density<<<NBATCH * GPB, TPB, 0, stream>>>(
        coords, atom_index, shifts, species, rs, inta, out);
}